// Round 5
// baseline (795.122 us; speedup 1.0000x reference)
//
#include <hip/hip_runtime.h>

typedef unsigned short u16;
typedef unsigned int u32;
using bf16x8 = __attribute__((ext_vector_type(8))) short;
using f32x4  = __attribute__((ext_vector_type(4))) float;

#define B_ 64
#define S_ 400
#define E_ 128
#define H_ 512
#define M_ 512
#define R_ (B_ * S_)   // 25600

__device__ __forceinline__ float b2f(u16 u){
  union { u32 i; float f; } c; c.i = ((u32)u) << 16; return c.f;
}
__device__ __forceinline__ u16 f2b(float f){
  union { u32 i; float f; } c; c.f = f;
  u32 r = c.i + 0x7FFFu + ((c.i >> 16) & 1u);
  return (u16)(r >> 16);
}
__device__ __forceinline__ float sigm(float x){ return 1.0f / (1.0f + __expf(-x)); }
__device__ __forceinline__ float fast_tanh(float x){
  float e = __expf(2.0f * x);
  return 1.0f - 2.0f / (e + 1.0f);
}
// pack 8 consecutive fp32 -> bf16x8 (truncate: take high u16 of each fp32)
__device__ __forceinline__ bf16x8 pack8(const float* __restrict__ p){
  const u32* u = (const u32*)p;
  union { u32 w[4]; bf16x8 v; } c;
  c.w[0] = (u[1] & 0xFFFF0000u) | (u[0] >> 16);
  c.w[1] = (u[3] & 0xFFFF0000u) | (u[2] >> 16);
  c.w[2] = (u[5] & 0xFFFF0000u) | (u[4] >> 16);
  c.w[3] = (u[7] & 0xFFFF0000u) | (u[6] >> 16);
  return c.v;
}

// ---------------- K0: zero the scores accumulator ----------------
__global__ void k0_zero(float* __restrict__ scores){
  int i = blockIdx.x * 256 + threadIdx.x;
  if (i < R_) scores[i] = 0.f;
}

// ---------------- K1: embedding gather + GRU step + dec_feat ----------------
__global__ __launch_bounds__(512) void k1_gru(
    const int* __restrict__ y, const float* __restrict__ h,
    const float* __restrict__ embW,
    const float* __restrict__ Wih, const float* __restrict__ Whh,
    const float* __restrict__ bih, const float* __restrict__ bhh,
    const float* __restrict__ Wd,  const float* __restrict__ bd,
    float* __restrict__ h1_ws, float* __restrict__ yemb_ws,
    float* __restrict__ dec_ws, float* __restrict__ h_out)
{
  __shared__ float emb_s[E_];
  __shared__ float h0_s[H_];
  __shared__ float h1_s[H_];
  int b = blockIdx.x, t = threadIdx.x;
  if (t < E_){ float e = embW[(size_t)y[b] * E_ + t]; emb_s[t] = e; yemb_ws[b*E_ + t] = e; }
  h0_s[t] = h[b*H_ + t];
  __syncthreads();
  int hh = t;
  float ir = bih[hh], iz = bih[hh+H_], in_ = bih[hh+2*H_];
  float hr = bhh[hh], hz = bhh[hh+H_], hn  = bhh[hh+2*H_];
  {
    const float* w0 = Wih + (size_t)hh*E_;
    const float* w1 = Wih + (size_t)(hh+H_)*E_;
    const float* w2 = Wih + (size_t)(hh+2*H_)*E_;
    for (int k = 0; k < E_; k += 4){
      float4 c0 = *(const float4*)(w0 + k);
      float4 c1 = *(const float4*)(w1 + k);
      float4 c2 = *(const float4*)(w2 + k);
      float x0 = emb_s[k], x1 = emb_s[k+1], x2 = emb_s[k+2], x3 = emb_s[k+3];
      ir += c0.x*x0 + c0.y*x1 + c0.z*x2 + c0.w*x3;
      iz += c1.x*x0 + c1.y*x1 + c1.z*x2 + c1.w*x3;
      in_+= c2.x*x0 + c2.y*x1 + c2.z*x2 + c2.w*x3;
    }
  }
  {
    const float* w0 = Whh + (size_t)hh*H_;
    const float* w1 = Whh + (size_t)(hh+H_)*H_;
    const float* w2 = Whh + (size_t)(hh+2*H_)*H_;
    for (int k = 0; k < H_; k += 4){
      float4 c0 = *(const float4*)(w0 + k);
      float4 c1 = *(const float4*)(w1 + k);
      float4 c2 = *(const float4*)(w2 + k);
      float x0 = h0_s[k], x1 = h0_s[k+1], x2 = h0_s[k+2], x3 = h0_s[k+3];
      hr += c0.x*x0 + c0.y*x1 + c0.z*x2 + c0.w*x3;
      hz += c1.x*x0 + c1.y*x1 + c1.z*x2 + c1.w*x3;
      hn += c2.x*x0 + c2.y*x1 + c2.z*x2 + c2.w*x3;
    }
  }
  float r = sigm(ir + hr);
  float z = sigm(iz + hz);
  float n = fast_tanh(in_ + r * hn);
  float h1v = (1.0f - z) * n + z * h0_s[hh];
  h1_s[hh] = h1v;
  h1_ws[b*H_ + hh] = h1v;
  h_out[b*H_ + hh] = h1v;
  __syncthreads();
  // dec_feat = h1 @ Wd^T + bd
  float acc = bd[hh];
  const float* wd = Wd + (size_t)hh*H_;
  for (int k = 0; k < H_; k += 4){
    float4 c = *(const float4*)(wd + k);
    acc += c.x*h1_s[k] + c.y*h1_s[k+1] + c.z*h1_s[k+2] + c.w*h1_s[k+3];
  }
  dec_ws[b*H_ + hh] = acc;
}

// ---------------- K2: MFMA enc GEMM fused with tanh()*v score reduce ----------------
// C[R,512] = mb[R,512] . Wm[512,512]^T ; score[R] += sum_h tanh(C+dec+cov*Wc)*v
// grid(400): block = 4 waves; wave w owns cols w*128..+127, rows rowB..rowB+63
__global__ __launch_bounds__(256) void k2_scores(
    const float* __restrict__ mb, const float* __restrict__ Wm,
    const float* __restrict__ dec, const float* __restrict__ cov,
    const float* __restrict__ Wc, const float* __restrict__ av,
    float* __restrict__ scores)
{
  int t = threadIdx.x;
  int lane = t & 63, w = t >> 6;
  int quad = lane >> 4, l16 = lane & 15;
  int rowB = blockIdx.x * 64;
  int cb = w * 128;
  f32x4 acc[4][8];
  #pragma unroll
  for (int rg = 0; rg < 4; rg++)
    #pragma unroll
    for (int j = 0; j < 8; j++) acc[rg][j] = (f32x4){0.f,0.f,0.f,0.f};
  for (int k0 = 0; k0 < H_; k0 += 32){
    bf16x8 af[4];
    #pragma unroll
    for (int rg = 0; rg < 4; rg++)
      af[rg] = pack8(mb + (size_t)(rowB + rg*16 + l16)*H_ + k0 + quad*8);
    #pragma unroll
    for (int j = 0; j < 8; j++){
      bf16x8 bfb = pack8(Wm + (size_t)(cb + j*16 + l16)*H_ + k0 + quad*8);
      #pragma unroll
      for (int rg = 0; rg < 4; rg++)
        acc[rg][j] = __builtin_amdgcn_mfma_f32_16x16x32_bf16(af[rg], bfb, acc[rg][j], 0, 0, 0);
    }
  }
  float vv[8], wcv[8];
  #pragma unroll
  for (int j = 0; j < 8; j++){
    int hc = cb + j*16 + l16;
    vv[j] = av[hc]; wcv[j] = Wc[hc];
  }
  #pragma unroll
  for (int rg = 0; rg < 4; rg++){
    #pragma unroll
    for (int r = 0; r < 4; r++){
      int R = rowB + rg*16 + quad*4 + r;   // C/D: row = quad*4 + reg
      int bb = R / S_;
      float cf = cov[R];
      const float* decb = dec + bb*H_;
      float sum = 0.f;
      #pragma unroll
      for (int j = 0; j < 8; j++){
        int hc = cb + j*16 + l16;          // C/D: col = lane&15
        float e = acc[rg][j][r] + decb[hc] + cf * wcv[j];
        sum += fast_tanh(e) * vv[j];
      }
      #pragma unroll
      for (int m = 1; m < 16; m <<= 1) sum += __shfl_xor(sum, m, 64);
      if (l16 == 0) atomicAdd(&scores[R], sum);
    }
  }
}

// ---------------- K3a: masked softmax + renorm; attn + coverage_next outputs ----------------
__global__ __launch_bounds__(256) void k3a_softmax(
    const float* __restrict__ scores, const float* __restrict__ mask,
    const float* __restrict__ cov,
    float* __restrict__ attn_ws,
    float* __restrict__ out_attn, float* __restrict__ out_cov)
{
  __shared__ float p_s[S_];
  __shared__ float m_s[S_];
  __shared__ float red[256];
  int b = blockIdx.x, t = threadIdx.x;
  float lmax = -3.0e38f;
  for (int s = t; s < S_; s += 256){
    float mk = mask[b*S_ + s];
    float v = scores[b*S_ + s];
    v = (mk > 0.f) ? v : -1e9f;
    p_s[s] = v; m_s[s] = mk;
    lmax = fmaxf(lmax, v);
  }
  red[t] = lmax; __syncthreads();
  for (int o = 128; o > 0; o >>= 1){ if (t < o) red[t] = fmaxf(red[t], red[t+o]); __syncthreads(); }
  float MX = red[0]; __syncthreads();
  float lsum = 0.f;
  for (int s = t; s < S_; s += 256){ float e = __expf(p_s[s] - MX); p_s[s] = e; lsum += e; }
  red[t] = lsum; __syncthreads();
  for (int o = 128; o > 0; o >>= 1){ if (t < o) red[t] += red[t+o]; __syncthreads(); }
  float inv1 = 1.0f / red[0]; __syncthreads();
  float l2 = 0.f;
  for (int s = t; s < S_; s += 256){ float a = p_s[s] * inv1 * m_s[s]; p_s[s] = a; l2 += a; }
  red[t] = l2; __syncthreads();
  for (int o = 128; o > 0; o >>= 1){ if (t < o) red[t] += red[t+o]; __syncthreads(); }
  float inv2 = 1.0f / (red[0] + 1e-10f); __syncthreads();
  for (int s = t; s < S_; s += 256){
    float a = p_s[s] * inv2;
    attn_ws[b*S_ + s] = a;
    out_attn[b*S_ + s] = a;
    out_cov[b*S_ + s]  = cov[b*S_ + s] + a;
  }
}

// ---------------- K3b: word_context GEMV: ctx[b,m] = sum_s attn[b,s]*mb[b,s,m] ----------------
// grid (64, 4): b, 128-wide m chunk; block 64 threads, each owns 2 m via float2
__global__ __launch_bounds__(64) void k3b_ctx(
    const float* __restrict__ attn_ws, const float* __restrict__ mb,
    float* __restrict__ ctx_ws, float* __restrict__ out_ctx)
{
  int b = blockIdx.x, t = threadIdx.x;
  int m0 = blockIdx.y * 128 + t * 2;
  const float* mbb = mb + (size_t)b * S_ * M_;
  const float* ab  = attn_ws + b * S_;
  float a0 = 0.f, a1 = 0.f;
  for (int s = 0; s < S_; s++){
    float a = ab[s];
    float2 c = *(const float2*)(mbb + s*M_ + m0);
    a0 += a * c.x;
    a1 += a * c.y;
  }
  ctx_ws[b*M_ + m0]    = a0; ctx_ws[b*M_ + m0+1]  = a1;
  out_ctx[b*M_ + m0]   = a0; out_ctx[b*M_ + m0+1] = a1;
}

// ---------------- K4: hid = [ctx,h1]@vd1^T + b (bf16 to ws); p_gen ----------------
__global__ __launch_bounds__(512) void k4_hid_pgen(
    const float* __restrict__ ctx_ws, const float* __restrict__ h1_ws,
    const float* __restrict__ yemb_ws,
    const float* __restrict__ vd1W, const float* __restrict__ vd1b,
    const float* __restrict__ pgW,  const float* __restrict__ pgb,
    u16* __restrict__ hid_bf, float* __restrict__ pgen_ws, float* __restrict__ out_pgen)
{
  __shared__ float vin[1024];
  __shared__ float red[512];
  int b = blockIdx.x, t = threadIdx.x;
  for (int i = t; i < 1024; i += 512)
    vin[i] = (i < 512) ? ctx_ws[b*512 + i] : h1_ws[b*512 + (i - 512)];
  __syncthreads();
  int hh = t;
  float acc = vd1b[hh];
  const float* wrow = vd1W + (size_t)hh * 1024;
  for (int k = 0; k < 1024; k += 4){
    float4 c = *(const float4*)(wrow + k);
    acc += c.x*vin[k] + c.y*vin[k+1] + c.z*vin[k+2] + c.w*vin[k+3];
  }
  hid_bf[b*512 + hh] = f2b(acc);
  float p = 0.f;
  for (int i = t; i < 1152; i += 512){
    float x = (i < 1024) ? vin[i] : yemb_ws[b*128 + (i - 1024)];
    p += x * pgW[i];
  }
  red[t] = p; __syncthreads();
  for (int o = 256; o > 0; o >>= 1){ if (t < o) red[t] += red[t+o]; __syncthreads(); }
  if (t == 0){
    float pg = sigm(red[0] + pgb[0]);
    pgen_ws[b] = pg; out_pgen[b] = pg;
  }
}

// ---------------- K5: MFMA logits GEMM: [64,V] = hid[64,512] . vd2W[V,512]^T ----------------
__global__ __launch_bounds__(256) void k5_logits(
    const u16* __restrict__ hid_bf, const float* __restrict__ vd2W,
    const float* __restrict__ vd2b, int V, u16* __restrict__ logits_bf)
{
  int t = threadIdx.x;
  int lane = t & 63, w = t >> 6;
  int quad = lane >> 4, l16 = lane & 15;
  int row0 = w * 16;                 // 4 waves cover rows 0..63
  int cb = blockIdx.x * 128;
  f32x4 acc[8];
  #pragma unroll
  for (int j = 0; j < 8; j++) acc[j] = (f32x4){0.f,0.f,0.f,0.f};
  const u16* arow = hid_bf + (size_t)(row0 + l16) * H_;
  for (int k0 = 0; k0 < H_; k0 += 32){
    bf16x8 a = *(const bf16x8*)(arow + k0 + quad*8);
    #pragma unroll
    for (int j = 0; j < 8; j++){
      int g = cb + j*16 + l16; if (g > V - 1) g = V - 1;   // clamp tail reads
      bf16x8 bfb = pack8(vd2W + (size_t)g*H_ + k0 + quad*8);
      acc[j] = __builtin_amdgcn_mfma_f32_16x16x32_bf16(a, bfb, acc[j], 0, 0, 0);
    }
  }
  #pragma unroll
  for (int j = 0; j < 8; j++){
    int v = cb + j*16 + l16;
    if (v < V){
      float bias = vd2b[v];
      #pragma unroll
      for (int r = 0; r < 4; r++){
        int bb = row0 + quad*4 + r;
        logits_bf[(size_t)bb*V + v] = f2b(acc[j][r] + bias);
      }
    }
  }
}

// ---------------- K6: per-b max & sum(exp) over V logits ----------------
__global__ __launch_bounds__(256) void k6_reduce(
    const u16* __restrict__ logits_bf, int V,
    float* __restrict__ mx_ws, float* __restrict__ den_ws)
{
  __shared__ float red[256];
  int b = blockIdx.x, t = threadIdx.x;
  const u16* row = logits_bf + (size_t)b * V;
  float m = -3.0e38f;
  for (int v = t; v < V; v += 256) m = fmaxf(m, b2f(row[v]));
  red[t] = m; __syncthreads();
  for (int o = 128; o > 0; o >>= 1){ if (t < o) red[t] = fmaxf(red[t], red[t+o]); __syncthreads(); }
  float MX = red[0]; __syncthreads();
  float s = 0.f;
  for (int v = t; v < V; v += 256) s += __expf(b2f(row[v]) - MX);
  red[t] = s; __syncthreads();
  for (int o = 128; o > 0; o >>= 1){ if (t < o) red[t] += red[t+o]; __syncthreads(); }
  if (t == 0){ mx_ws[b] = MX; den_ws[b] = red[0]; }
}

// ---------------- K7a: out_final[b,c] = p_gen * softmax(logits) (fp32), 0 for OOV cols ----------------
__global__ void k7a_vocab(const u16* __restrict__ logits_bf,
    const float* __restrict__ mx_ws, const float* __restrict__ den_ws,
    const float* __restrict__ pgen_ws, int V, int VO, float* __restrict__ out_final)
{
  int b = blockIdx.y;
  int c = blockIdx.x * 256 + threadIdx.x;
  if (c >= VO) return;
  float val = 0.f;
  if (c < V)
    val = pgen_ws[b] * __expf(b2f(logits_bf[(size_t)b*V + c]) - mx_ws[b]) / den_ws[b];
  out_final[(size_t)b*VO + c] = val;
}

// ---------------- K7b: scatter-add (1-p_gen)*attn at src_oov (fp32 atomic) ----------------
__global__ void k7b_scatter(const int* __restrict__ src_oov,
    const float* __restrict__ attn_ws, const float* __restrict__ pgen_ws,
    int VO, float* __restrict__ out_final)
{
  int idx = blockIdx.x * 256 + threadIdx.x;
  if (idx >= R_) return;
  int b = idx / S_;
  float ad = (1.0f - pgen_ws[b]) * attn_ws[idx];
  atomicAdd(&out_final[(size_t)b*VO + src_oov[idx]], ad);
}

extern "C" void kernel_launch(void* const* d_in, const int* in_sizes, int n_in,
                              void* d_out, int out_size, void* d_ws, size_t ws_size,
                              hipStream_t stream)
{
  const int*   y      = (const int*)d_in[0];
  const float* h      = (const float*)d_in[1];
  const float* mb     = (const float*)d_in[2];
  const float* mask   = (const float*)d_in[3];
  const int*   srcoov = (const int*)d_in[5];
  const float* cov    = (const float*)d_in[6];
  const float* embW   = (const float*)d_in[7];
  const float* Wih    = (const float*)d_in[8];
  const float* Whh    = (const float*)d_in[9];
  const float* bih    = (const float*)d_in[10];
  const float* bhh    = (const float*)d_in[11];
  const float* Wm     = (const float*)d_in[12];
  const float* Wd     = (const float*)d_in[13];
  const float* bd     = (const float*)d_in[14];
  const float* Wc     = (const float*)d_in[15];
  const float* av     = (const float*)d_in[16];
  const float* pgW    = (const float*)d_in[17];
  const float* pgb    = (const float*)d_in[18];
  const float* vd1W   = (const float*)d_in[19];
  const float* vd1b   = (const float*)d_in[20];
  const float* vd2W   = (const float*)d_in[21];
  const float* vd2b   = (const float*)d_in[22];

  // dynamic dims: V from vd2_b size; VO from out_size (fp32 elements):
  // out_size = B*(VO + H + M + 2S + 1)
  const int V  = in_sizes[22];
  const int VO = (int)((long long)out_size / B_ - (H_ + M_ + 2*S_ + 1));

  float* out = (float*)d_out;
  float* out_final = out;                                 // [B, VO]
  float* out_h     = out_final + (size_t)B_ * VO;         // [1,B,H]
  float* out_ctx   = out_h     + (size_t)B_ * H_;         // [B,M]
  float* out_attn  = out_ctx   + (size_t)B_ * M_;         // [B,S]
  float* out_pgen  = out_attn  + (size_t)B_ * S_;         // [B,1]
  float* out_cov   = out_pgen  + B_;                      // [B,S]

  float* ws      = (float*)d_ws;
  float* scores  = ws;                        // 25600
  float* h1_ws   = ws + 25600;                // 32768
  float* yemb_ws = ws + 58368;                // 8192
  float* dec_ws  = ws + 66560;                // 32768
  float* attn_ws = ws + 99328;                // 25600
  float* ctx_ws  = ws + 124928;               // 32768
  float* pgen_ws = ws + 157696;               // 64
  float* mx_ws   = ws + 157760;               // 64
  float* den_ws  = ws + 157824;               // 64
  u16*   hid_bf    = (u16*)(ws + 157888);     // 32768 u16
  u16*   logits_bf = (u16*)(ws + 174272);     // B*V u16 (~6.4 MB)

  hipLaunchKernelGGL(k0_zero,    dim3(100),  dim3(256), 0, stream, scores);
  hipLaunchKernelGGL(k1_gru,     dim3(64),   dim3(512), 0, stream,
                     y, h, embW, Wih, Whh, bih, bhh, Wd, bd, h1_ws, yemb_ws, dec_ws, out_h);
  hipLaunchKernelGGL(k2_scores,  dim3(400),  dim3(256), 0, stream,
                     mb, Wm, dec_ws, cov, Wc, av, scores);
  hipLaunchKernelGGL(k3a_softmax, dim3(64),  dim3(256), 0, stream,
                     scores, mask, cov, attn_ws, out_attn, out_cov);
  hipLaunchKernelGGL(k3b_ctx,    dim3(64, 4), dim3(64), 0, stream,
                     attn_ws, mb, ctx_ws, out_ctx);
  hipLaunchKernelGGL(k4_hid_pgen, dim3(64),  dim3(512), 0, stream,
                     ctx_ws, h1_ws, yemb_ws, vd1W, vd1b, pgW, pgb, hid_bf, pgen_ws, out_pgen);
  hipLaunchKernelGGL(k5_logits,  dim3((V + 127) / 128), dim3(256), 0, stream,
                     hid_bf, vd2W, vd2b, V, logits_bf);
  hipLaunchKernelGGL(k6_reduce,  dim3(64),   dim3(256), 0, stream, logits_bf, V, mx_ws, den_ws);
  hipLaunchKernelGGL(k7a_vocab,  dim3((VO + 255) / 256, 64), dim3(256), 0, stream,
                     logits_bf, mx_ws, den_ws, pgen_ws, V, VO, out_final);
  hipLaunchKernelGGL(k7b_scatter, dim3(100), dim3(256), 0, stream,
                     srcoov, attn_ws, pgen_ws, VO, out_final);
}